// Round 1
// baseline (395.211 us; speedup 1.0000x reference)
//
#include <hip/hip_runtime.h>

#define T_  4
#define B_  2
#define C_  384
#define L_  1024
#define H_  8
#define D_  48
#define C2_ 768
#define S_  (B_*C_*L_)   // 786432 elements per time step

// ---------------- K1/K5: mem_update scan over T, emits 0/1 spikes ----------
__global__ __launch_bounds__(256) void spike_scan(const float* __restrict__ src,
                                                  float* __restrict__ dst) {
    int i = blockIdx.x * 256 + threadIdx.x;
    float mem = 0.f, s = 0.f;
#pragma unroll
    for (int t = 0; t < T_; t++) {
        mem = mem * 0.25f * (1.f - s) + src[(size_t)t * S_ + i];
        s = (mem > 0.5f) ? 1.f : 0.f;
        dst[(size_t)t * S_ + i] = s;
    }
}

// ---------------- K2/K6: Y = BN(W @ X) (+ residual), K=384 -----------------
// W: (M,384) row-major; X: (batch, 384, 1024); out: (batch, M, 1024)
template <int RES>
__global__ __launch_bounds__(256) void gemm_bn(
    const float* __restrict__ W, const float* __restrict__ X,
    const float* __restrict__ gamma, const float* __restrict__ beta,
    const float* __restrict__ mean, const float* __restrict__ var,
    const float* __restrict__ res, float* __restrict__ out, int M) {
    __shared__ float W_s[16][68];   // [k][m], padded: 272B row stride, 16B aligned
    __shared__ float X_s[16][64];   // [k][n]
    const int tid = threadIdx.x;
    const int batch = blockIdx.y;
    const int mt = blockIdx.x >> 4, nt = blockIdx.x & 15;
    const int om = mt * 64, ln = nt * 64;
    const float* Xb = X + (size_t)batch * C_ * L_;
    const int tx = tid & 15, ty = tid >> 4;

    const int e = tid * 4;
    const int wo = e >> 4, wc = e & 15;    // W tile: 64 rows x 16 k
    const int xc = e >> 6, xl = e & 63;    // X tile: 16 k x 64 cols

    float acc[4][4] = {};
    for (int ck = 0; ck < C_; ck += 16) {
        float4 wv = *(const float4*)(W + (size_t)(om + wo) * C_ + ck + wc);
        float4 xv = *(const float4*)(Xb + (size_t)(ck + xc) * L_ + ln + xl);
        W_s[wc + 0][wo] = wv.x; W_s[wc + 1][wo] = wv.y;
        W_s[wc + 2][wo] = wv.z; W_s[wc + 3][wo] = wv.w;
        *(float4*)&X_s[xc][xl] = xv;
        __syncthreads();
#pragma unroll
        for (int kk = 0; kk < 16; kk++) {
            float av[4], bv[4];
            *(float4*)av = *(const float4*)&W_s[kk][ty * 4];
            *(float4*)bv = *(const float4*)&X_s[kk][tx * 4];
#pragma unroll
            for (int i = 0; i < 4; i++)
#pragma unroll
                for (int j = 0; j < 4; j++) acc[i][j] += av[i] * bv[j];
        }
        __syncthreads();
    }
#pragma unroll
    for (int i = 0; i < 4; i++) {
        const int o = om + ty * 4 + i;
        const float inv = gamma[o] / sqrtf(var[o] + 1e-5f);
        const float sh = beta[o] - mean[o] * inv;
        float4 r;
        r.x = acc[i][0] * inv + sh; r.y = acc[i][1] * inv + sh;
        r.z = acc[i][2] * inv + sh; r.w = acc[i][3] * inv + sh;
        const size_t off = ((size_t)batch * M + o) * L_ + ln + tx * 4;
        if (RES) {
            float4 rv = *(const float4*)(res + off);
            r.x += rv.x; r.y += rv.y; r.z += rv.z; r.w += rv.w;
        }
        *(float4*)(out + off) = r;
    }
}

// ---------------- K3: attn = y1^T @ xr, t-scan in registers, bit-packed ----
// attn[l,m] = sum_d y1[d,l]*xr[d,m]; scan over t; emit spike bits (m-packed)
__global__ __launch_bounds__(256) void attn_spike(
    const float* __restrict__ y, const float* __restrict__ xs,
    unsigned* __restrict__ bits) {
    __shared__ float A_s[D_][64];       // y1 [d][l]
    __shared__ float B_s[D_][64];       // xr [d][m]
    __shared__ unsigned bits_s[64][2];
    const int tid = threadIdx.x;
    const int b = blockIdx.y >> 3, h = blockIdx.y & 7;
    const int lbase = (blockIdx.x >> 4) * 64, mbase = (blockIdx.x & 15) * 64;
    const int tx = tid & 15, ty = tid >> 4;

    float mem[4][4], sp[4][4];
#pragma unroll
    for (int i = 0; i < 4; i++)
#pragma unroll
        for (int j = 0; j < 4; j++) { mem[i][j] = 0.f; sp[i][j] = 0.f; }

    for (int t = 0; t < T_; t++) {
#pragma unroll
        for (int p = 0; p < 3; p++) {
            const int ee = p * 1024 + tid * 4;
            const int dd = ee >> 6, col = ee & 63;
            *(float4*)&A_s[dd][col] =
                *(const float4*)(y + ((size_t)(t * B_ + b) * C2_ + h * 96 + dd) * L_ + lbase + col);
            *(float4*)&B_s[dd][col] =
                *(const float4*)(xs + ((size_t)(t * B_ + b) * C_ + h * D_ + dd) * L_ + mbase + col);
        }
        if (tid < 128) bits_s[tid >> 1][tid & 1] = 0u;
        __syncthreads();

        float acc[4][4] = {};
#pragma unroll 4
        for (int dd = 0; dd < D_; dd++) {
            float av[4], bv[4];
            *(float4*)av = *(const float4*)&A_s[dd][ty * 4];
            *(float4*)bv = *(const float4*)&B_s[dd][tx * 4];
#pragma unroll
            for (int i = 0; i < 4; i++)
#pragma unroll
                for (int j = 0; j < 4; j++) acc[i][j] += av[i] * bv[j];
        }

#pragma unroll
        for (int i = 0; i < 4; i++) {
            unsigned nib = 0;
#pragma unroll
            for (int j = 0; j < 4; j++) {
                mem[i][j] = mem[i][j] * 0.25f * (1.f - sp[i][j]) + acc[i][j];
                sp[i][j] = (mem[i][j] > 0.5f) ? 1.f : 0.f;
                if (mem[i][j] > 0.5f) nib |= (1u << j);
            }
            atomicOr(&bits_s[ty * 4 + i][tx >> 3], nib << ((tx & 7) * 4));
        }
        __syncthreads();
        if (tid < 128) {
            const int l = tid >> 1, w = tid & 1;
            const size_t wi =
                ((size_t)((t * B_ + b) * H_ + h) * L_ + lbase + l) * (L_ / 32) + (mbase >> 5) + w;
            bits[wi] = bits_s[l][w];
        }
        __syncthreads();
    }
}

// ---------------- K4: outpre[d,m] = sum_l y2[d,l] * spike(l,m) -------------
__global__ __launch_bounds__(256) void attn_out(
    const float* __restrict__ y, const unsigned* __restrict__ bits,
    float* __restrict__ outpre) {
    __shared__ float y2_s[D_][64];      // [d][l]
    __shared__ unsigned mask_s[64][4];  // [l][word], 128 m-bits
    const int tid = threadIdx.x;
    const int tbh = blockIdx.y;
    const int t = tbh >> 4, b = (tbh >> 3) & 1, h = tbh & 7;
    const int mbase = blockIdx.x * 128;
    const int tx = tid & 31, ty = tid >> 5;
    const int sh = (tx & 7) * 4;

    float acc[6][4] = {};
    for (int lt = 0; lt < L_; lt += 64) {
#pragma unroll
        for (int p = 0; p < 3; p++) {
            const int ee = p * 1024 + tid * 4;
            const int dd = ee >> 6, col = ee & 63;
            *(float4*)&y2_s[dd][col] =
                *(const float4*)(y + ((size_t)(t * B_ + b) * C2_ + h * 96 + 48 + dd) * L_ + lt + col);
        }
        {
            const int l = tid >> 2, w = tid & 3;
            mask_s[l][w] =
                bits[((size_t)((t * B_ + b) * H_ + h) * L_ + lt + l) * (L_ / 32) + (mbase >> 5) + w];
        }
        __syncthreads();

        for (int l0 = 0; l0 < 64; l0 += 4) {
            float yv[6][4];
#pragma unroll
            for (int dd = 0; dd < 6; dd++)
                *(float4*)yv[dd] = *(const float4*)&y2_s[ty * 6 + dd][l0];
#pragma unroll
            for (int lo = 0; lo < 4; lo++) {
                const unsigned bw = mask_s[l0 + lo][tx >> 3];
                float f[4];
#pragma unroll
                for (int j = 0; j < 4; j++) f[j] = ((bw >> (sh + j)) & 1u) ? 1.f : 0.f;
#pragma unroll
                for (int dd = 0; dd < 6; dd++)
#pragma unroll
                    for (int j = 0; j < 4; j++) acc[dd][j] += yv[dd][lo] * f[j];
            }
        }
        __syncthreads();
    }
#pragma unroll
    for (int dd = 0; dd < 6; dd++) {
        const int c = h * D_ + ty * 6 + dd;
        float4 r = {acc[dd][0], acc[dd][1], acc[dd][2], acc[dd][3]};
        *(float4*)(outpre + ((size_t)(t * B_ + b) * C_ + c) * L_ + mbase + tx * 4) = r;
    }
}

extern "C" void kernel_launch(void* const* d_in, const int* in_sizes, int n_in,
                              void* d_out, int out_size, void* d_ws, size_t ws_size,
                              hipStream_t stream) {
    const float* x   = (const float*)d_in[0];
    const float* W_w = (const float*)d_in[1];
    const float* g1  = (const float*)d_in[2];
    const float* b1  = (const float*)d_in[3];
    const float* m1  = (const float*)d_in[4];
    const float* v1  = (const float*)d_in[5];
    const float* pw  = (const float*)d_in[6];
    const float* g2  = (const float*)d_in[7];
    const float* b2  = (const float*)d_in[8];
    const float* m2  = (const float*)d_in[9];
    const float* v2  = (const float*)d_in[10];

    float* ws = (float*)d_ws;
    float*    xs     = ws;                              // 3,145,728 f
    float*    y      = ws + 3145728;                    // 6,291,456 f
    unsigned* bits   = (unsigned*)(ws + 9437184);       // 2,097,152 words
    float*    outpre = ws + 11534336;                   // 3,145,728 f
    float*    outs   = xs;                              // alias (xs dead after K3)
    float*    out    = (float*)d_out;                   // total ws use: 56 MB

    // 1) xs = spikes(mem_update(x))
    spike_scan<<<dim3(S_ / 256), 256, 0, stream>>>(x, xs);
    // 2) y = BN1(W_w @ xs)     M=768 -> 12 mtiles x 16 ntiles
    gemm_bn<0><<<dim3(192, 8), 256, 0, stream>>>(W_w, xs, g1, b1, m1, v1, nullptr, y, C2_);
    // 3) attn spikes (scan over t in registers), bit-packed
    attn_spike<<<dim3(256, 16), 256, 0, stream>>>(y, xs, bits);
    // 4) outpre = y2 @ attn_spikes
    attn_out<<<dim3(8, 64), 256, 0, stream>>>(y, bits, outpre);
    // 5) outs = spikes(mem_update(outpre))
    spike_scan<<<dim3(S_ / 256), 256, 0, stream>>>(outpre, outs);
    // 6) out = BN2(proj_w @ outs) + x    M=384 -> 6 mtiles x 16 ntiles
    gemm_bn<1><<<dim3(96, 8), 256, 0, stream>>>(pw, outs, g2, b2, m2, v2, x, out, C_);
}